// Round 1
// 397.485 us; speedup vs baseline: 1.0905x; 1.0905x over previous
//
#include <hip/hip_runtime.h>
#include <math.h>

#define N_NODES 100000
#define E_EDGES 3200000
#define IN_DIM_ 128
#define HID_ 64
#define BN_EPS_ 1e-5f

#define PB 250          // edge-chunk blocks
#define CHUNK 12800     // E / PB exactly
#define NBUCK 391       // ceil(N / 256): bucket = dst >> 8
#define BMAX 9600       // passB LDS sort capacity (mean 8184, 15 sigma)

typedef __attribute__((ext_vector_type(8))) short short8;
typedef __attribute__((ext_vector_type(4))) float f32x4;
typedef __attribute__((ext_vector_type(2))) float f32x2;

__device__ inline ushort f2bf(float f) {
    union { float f; unsigned u; } c; c.f = f;
    unsigned r = c.u + 0x7fff + ((c.u >> 16) & 1);   // RNE
    return (ushort)(r >> 16);
}
__device__ inline float bf_lo(unsigned p) { union { unsigned u; float f; } c; c.u = p << 16; return c.f; }
__device__ inline float bf_hi(unsigned p) { union { unsigned u; float f; } c; c.u = p & 0xffff0000u; return c.f; }
__device__ inline f32x2 up2(unsigned u) {
    union { unsigned u; float f; } lo, hi;
    lo.u = u << 16; hi.u = u & 0xffff0000u;
    f32x2 r; r.x = lo.f; r.y = hi.f; return r;
}

// ---------------- pass A1: per-block bucket histogram ----------------
__global__ __launch_bounds__(512) void passA1_hist(const int* __restrict__ ei,
                                                   int* __restrict__ histPB) {
    __shared__ int hist[NBUCK];
    int t = threadIdx.x, b = blockIdx.x;
    for (int k = t; k < NBUCK; k += 512) hist[k] = 0;
    __syncthreads();
    int e0 = b * CHUNK, e1 = e0 + CHUNK;
    for (int e = e0 + t; e < e1; e += 512) {
        int d = ei[E_EDGES + e];
        atomicAdd(&hist[d >> 8], 1);
    }
    __syncthreads();
    for (int k = t; k < NBUCK; k += 512) histPB[k * PB + b] = hist[k];
}

// ---------------- per-bucket row scan ----------------
__global__ __launch_bounds__(256) void scan_rows(int* __restrict__ histPB,
                                                 int* __restrict__ bucket_tot) {
    __shared__ int wsum[4];
    int k = blockIdx.x, t = threadIdx.x, lane = t & 63, wv = t >> 6;
    int v = (t < PB) ? histPB[k * PB + t] : 0;
    int s = v;
#pragma unroll
    for (int off = 1; off < 64; off <<= 1) {
        int u = __shfl_up(s, off, 64);
        if (lane >= off) s += u;
    }
    if (lane == 63) wsum[wv] = s;
    __syncthreads();
    int wbase = 0;
    for (int w = 0; w < wv; w++) wbase += wsum[w];
    if (t < PB) histPB[k * PB + t] = wbase + s - v;
    if (t == 255) bucket_tot[k] = wbase + s;
}

// ---------------- scan bucket totals -> bucket_base ----------------
__global__ __launch_bounds__(512) void scan_totals(const int* __restrict__ bucket_tot,
                                                   int* __restrict__ bucket_base,
                                                   int* __restrict__ row_ptr) {
    __shared__ int wsum[8];
    int t = threadIdx.x, lane = t & 63, wv = t >> 6;
    int v = (t < NBUCK) ? bucket_tot[t] : 0;
    int s = v;
#pragma unroll
    for (int off = 1; off < 64; off <<= 1) {
        int u = __shfl_up(s, off, 64);
        if (lane >= off) s += u;
    }
    if (lane == 63) wsum[wv] = s;
    __syncthreads();
    int wbase = 0;
    for (int w = 0; w < wv; w++) wbase += wsum[w];
    if (t < NBUCK) bucket_base[t] = wbase + s - v;
    if (t == 0) {
        bucket_base[NBUCK] = E_EDGES;
        row_ptr[N_NODES] = E_EDGES;
    }
}

// ---- pass A2: LDS counting sort per chunk -> COALESCED ebuf writes ----
__global__ __launch_bounds__(512) void passA2_sorted(const int* __restrict__ ei,
                                                     const int* __restrict__ histPB,
                                                     const int* __restrict__ bucket_base,
                                                     int* __restrict__ ebuf) {
    __shared__ int sorted[CHUNK];     // 51.2 KB
    __shared__ ushort bid[CHUNK];     // 25.6 KB
    __shared__ int cur[NBUCK];
    __shared__ int lbase[NBUCK];
    int t = threadIdx.x, b = blockIdx.x;
    for (int k = t; k < NBUCK; k += 512) cur[k] = 0;
    __syncthreads();
    int e0 = b * CHUNK;
    // (a) local histogram
    for (int e = e0 + t; e < e0 + CHUNK; e += 512)
        atomicAdd(&cur[ei[E_EDGES + e] >> 8], 1);
    __syncthreads();
    // (b) exclusive scan cur -> lbase (single wave, chunks of 64)
    if (t < 64) {
        int run = 0;
        for (int c0 = 0; c0 < NBUCK; c0 += 64) {
            int idx = c0 + t;
            int v = (idx < NBUCK) ? cur[idx] : 0;
            int s = v;
#pragma unroll
            for (int off = 1; off < 64; off <<= 1) {
                int u = __shfl_up(s, off, 64);
                if (t >= off) s += u;
            }
            if (idx < NBUCK) lbase[idx] = run + s - v;
            run += __shfl(s, 63, 64);
        }
    }
    __syncthreads();
    for (int k = t; k < NBUCK; k += 512) cur[k] = lbase[k];
    __syncthreads();
    // (c) place into LDS (re-read ei; L2-hot)
    for (int e = e0 + t; e < e0 + CHUNK; e += 512) {
        int s = ei[e];
        int d = ei[E_EDGES + e];
        int k = d >> 8;
        int pos = atomicAdd(&cur[k], 1);
        sorted[pos] = s | ((d & 255) << 17);
        bid[pos] = (ushort)k;
    }
    __syncthreads();
    // (d) coalesced write-out (runs are contiguous per bucket)
    for (int j = t; j < CHUNK; j += 512) {
        int k = bid[j];
        int dest = bucket_base[k] + histPB[k * PB + b] + (j - lbase[k]);
        ebuf[dest] = sorted[j];
    }
}

// ---- pass B: LDS sort per bucket -> COALESCED csr writes + row_ptr + dinv ----
__global__ __launch_bounds__(256) void passB_sorted(const int* __restrict__ ebuf,
                                                    const int* __restrict__ bucket_base,
                                                    int* __restrict__ row_ptr,
                                                    int* __restrict__ csr_src,
                                                    float* __restrict__ dinv) {
    __shared__ int sorted[BMAX];      // 38.4 KB
    __shared__ int hist[256];
    __shared__ int wsum[4];
    int b = blockIdx.x, t = threadIdx.x, lane = t & 63, wv = t >> 6;
    int base = bucket_base[b], end = bucket_base[b + 1];
    hist[t] = 0;
    __syncthreads();
    for (int k = base + t; k < end; k += 256)
        atomicAdd(&hist[ebuf[k] >> 17], 1);
    __syncthreads();
    int v = hist[t];
    int s = v;
#pragma unroll
    for (int off = 1; off < 64; off <<= 1) {
        int u = __shfl_up(s, off, 64);
        if (lane >= off) s += u;
    }
    if (lane == 63) wsum[wv] = s;
    __syncthreads();
    int wbase = 0;
    for (int w = 0; w < wv; w++) wbase += wsum[w];
    int excl = wbase + s - v;
    int node = b * 256 + t;
    if (node < N_NODES) {
        row_ptr[node] = base + excl;
        dinv[node] = rsqrtf((float)v + 1.0f);
    }
    __syncthreads();
    hist[t] = excl;  // reuse as cursor
    __syncthreads();
    for (int k = base + t; k < end; k += 256) {
        int pv = ebuf[k];
        int pos = atomicAdd(&hist[pv >> 17], 1);
        if (pos < BMAX) sorted[pos] = pv;
        else csr_src[base + pos] = pv & 0x1FFFF;   // overflow safety valve
    }
    __syncthreads();
    int cnt = end - base;
    if (cnt > BMAX) cnt = BMAX;
    for (int j = t; j < cnt; j += 256)
        csr_src[base + j] = sorted[j] & 0x1FFFF;
}

// ---------------- MFMA GEMM: hs(bf16) = (X @ W) * dinv[row] ----------------
// Also writes a ZERO row at hs[N_NODES] (used by gather_feat as the dummy
// target for masked-out gather slots).
template<int K, bool BF16IN>
__global__ __launch_bounds__(256) void gemm_bf16(const void* __restrict__ Xv,
                                                 const float* __restrict__ W,   // [K][64]
                                                 const float* __restrict__ dinv,
                                                 ushort* __restrict__ hs) {     // [N+1][64] bf16
    constexpr int KP = K + 8;
    __shared__ ushort A_lds[64][KP];
    __shared__ ushort Wt_lds[64][KP];
    int t = threadIdx.x;
    long row0 = (long)blockIdx.x * 64;

    for (int i = t; i < K * 16; i += 256) {
        float4 w4 = ((const float4*)W)[i];
        int k = i >> 4, n = (i & 15) * 4;
        Wt_lds[n + 0][k] = f2bf(w4.x);
        Wt_lds[n + 1][k] = f2bf(w4.y);
        Wt_lds[n + 2][k] = f2bf(w4.z);
        Wt_lds[n + 3][k] = f2bf(w4.w);
    }
    if (BF16IN) {
        constexpr int K2 = K / 2;
        const unsigned* X = (const unsigned*)Xv;
        for (int i = t; i < 64 * K2; i += 256) {
            int r = i / K2, c = i % K2;
            unsigned val = 0;
            long row = row0 + r;
            if (row < N_NODES) val = X[row * K2 + c];
            *(unsigned*)&A_lds[r][c * 2] = val;
        }
    } else {
        constexpr int K4 = K / 4;
        const float* X = (const float*)Xv;
        for (int i = t; i < 64 * K4; i += 256) {
            int r = i / K4, c = i % K4;
            float4 val = make_float4(0.f, 0.f, 0.f, 0.f);
            long row = row0 + r;
            if (row < N_NODES) val = ((const float4*)X)[row * K4 + c];
            int cb = c * 4;
            A_lds[r][cb + 0] = f2bf(val.x);
            A_lds[r][cb + 1] = f2bf(val.y);
            A_lds[r][cb + 2] = f2bf(val.z);
            A_lds[r][cb + 3] = f2bf(val.w);
        }
    }
    __syncthreads();

    int w = t >> 6, l = t & 63;
    int m = l & 15, quad = l >> 4;
    f32x4 acc[4];
#pragma unroll
    for (int c = 0; c < 4; c++) acc[c] = (f32x4){0.f, 0.f, 0.f, 0.f};

#pragma unroll
    for (int ch = 0; ch < K / 32; ch++) {
        short8 a = *(const short8*)&A_lds[16 * w + m][32 * ch + 8 * quad];
#pragma unroll
        for (int c = 0; c < 4; c++) {
            short8 b = *(const short8*)&Wt_lds[16 * c + m][32 * ch + 8 * quad];
            acc[c] = __builtin_amdgcn_mfma_f32_16x16x32_bf16(a, b, acc[c], 0, 0, 0);
        }
    }

#pragma unroll
    for (int r = 0; r < 4; r++) {
        long node = row0 + 16 * w + quad * 4 + r;
        if (node <= N_NODES) {                       // include zero row N
            float dv = (node < N_NODES) ? dinv[node] : 0.f;
#pragma unroll
            for (int c = 0; c < 4; c++)
                hs[node * 64 + 16 * c + m] = f2bf(acc[c][r] * dv);
        }
    }
}

// ---------------- pull-gather: batched 32-edge epochs, branch-free tail ----
// 64 lanes = 8 edge-slots (es) x 8 feature-groups (fg, uint4 each).
// Per iteration each lane issues 4 independent csr-index loads and 4
// independent uint4 gathers (invalid slots -> zero row at hs[N]).
template<bool LAST>
__global__ __launch_bounds__(256) void gather_feat(const int* __restrict__ row_ptr,
                                                   const int* __restrict__ csr_src,
                                                   const ushort* __restrict__ hs,
                                                   const float* __restrict__ dinv,
                                                   const float* __restrict__ b,
                                                   const float* __restrict__ g,
                                                   const float* __restrict__ beta,
                                                   const float* __restrict__ m,
                                                   const float* __restrict__ v,
                                                   unsigned* __restrict__ y,
                                                   const float* __restrict__ W3,
                                                   float* __restrict__ hs3, int n) {
    int i = (blockIdx.x * 256 + threadIdx.x) >> 6;
    if (i >= n) return;
    int l = threadIdx.x & 63;
    int es = l >> 3, fg = l & 7;
    const char* Hb = (const char*)hs;
    unsigned foff = (unsigned)fg << 4;
    unsigned zoff = ((unsigned)N_NODES << 7) + foff;   // zero-row offset

    f32x2 a01 = {0.f, 0.f}, a23 = {0.f, 0.f}, a45 = {0.f, 0.f}, a67 = {0.f, 0.f};

    if (es == 0) {   // self-loop
        uint4 p = *(const uint4*)(Hb + (((unsigned)i << 7) + foff));
        a01 += up2(p.x); a23 += up2(p.y); a45 += up2(p.z); a67 += up2(p.w);
    }

    int beg = row_ptr[i], end = row_ptr[i + 1];
    int endm1 = end - 1;
    for (int k = beg + es; k < end; k += 32) {
        int c1 = k + 8, c2 = k + 16, c3 = k + 24;
        // 4 independent index loads (replicated across fg -> one line each)
        int s0 = csr_src[k];
        int s1 = csr_src[c1 < end ? c1 : endm1];
        int s2 = csr_src[c2 < end ? c2 : endm1];
        int s3 = csr_src[c3 < end ? c3 : endm1];
        unsigned o0 = ((unsigned)s0 << 7) + foff;
        unsigned o1 = (c1 < end) ? (((unsigned)s1 << 7) + foff) : zoff;
        unsigned o2 = (c2 < end) ? (((unsigned)s2 << 7) + foff) : zoff;
        unsigned o3 = (c3 < end) ? (((unsigned)s3 << 7) + foff) : zoff;
        // 4 independent row gathers in flight
        uint4 p0 = *(const uint4*)(Hb + o0);
        uint4 p1 = *(const uint4*)(Hb + o1);
        uint4 p2 = *(const uint4*)(Hb + o2);
        uint4 p3 = *(const uint4*)(Hb + o3);
        a01 += up2(p0.x); a23 += up2(p0.y); a45 += up2(p0.z); a67 += up2(p0.w);
        a01 += up2(p1.x); a23 += up2(p1.y); a45 += up2(p1.z); a67 += up2(p1.w);
        a01 += up2(p2.x); a23 += up2(p2.y); a45 += up2(p2.z); a67 += up2(p2.w);
        a01 += up2(p3.x); a23 += up2(p3.y); a45 += up2(p3.z); a67 += up2(p3.w);
    }

    float a0 = a01.x, a1 = a01.y, a2 = a23.x, a3 = a23.y;
    float a4 = a45.x, a5 = a45.y, a6 = a67.x, a7 = a67.y;

#pragma unroll
    for (int off = 8; off < 64; off <<= 1) {
        a0 += __shfl_xor(a0, off, 64);
        a1 += __shfl_xor(a1, off, 64);
        a2 += __shfl_xor(a2, off, 64);
        a3 += __shfl_xor(a3, off, 64);
        a4 += __shfl_xor(a4, off, 64);
        a5 += __shfl_xor(a5, off, 64);
        a6 += __shfl_xor(a6, off, 64);
        a7 += __shfl_xor(a7, off, 64);
    }

    float4 bb0 = ((const float4*)b)[fg * 2],    bb1 = ((const float4*)b)[fg * 2 + 1];
    float4 gg0 = ((const float4*)g)[fg * 2],    gg1 = ((const float4*)g)[fg * 2 + 1];
    float4 be0 = ((const float4*)beta)[fg * 2], be1 = ((const float4*)beta)[fg * 2 + 1];
    float4 mm0 = ((const float4*)m)[fg * 2],    mm1 = ((const float4*)m)[fg * 2 + 1];
    float4 vv0 = ((const float4*)v)[fg * 2],    vv1 = ((const float4*)v)[fg * 2 + 1];
    float di = dinv[i];
    float o0 = fmaxf((di * a0 + bb0.x - mm0.x) * (gg0.x * rsqrtf(vv0.x + BN_EPS_)) + be0.x, 0.f);
    float o1 = fmaxf((di * a1 + bb0.y - mm0.y) * (gg0.y * rsqrtf(vv0.y + BN_EPS_)) + be0.y, 0.f);
    float o2 = fmaxf((di * a2 + bb0.z - mm0.z) * (gg0.z * rsqrtf(vv0.z + BN_EPS_)) + be0.z, 0.f);
    float o3 = fmaxf((di * a3 + bb0.w - mm0.w) * (gg0.w * rsqrtf(vv0.w + BN_EPS_)) + be0.w, 0.f);
    float o4 = fmaxf((di * a4 + bb1.x - mm1.x) * (gg1.x * rsqrtf(vv1.x + BN_EPS_)) + be1.x, 0.f);
    float o5 = fmaxf((di * a5 + bb1.y - mm1.y) * (gg1.y * rsqrtf(vv1.y + BN_EPS_)) + be1.y, 0.f);
    float o6 = fmaxf((di * a6 + bb1.z - mm1.z) * (gg1.z * rsqrtf(vv1.z + BN_EPS_)) + be1.z, 0.f);
    float o7 = fmaxf((di * a7 + bb1.w - mm1.w) * (gg1.w * rsqrtf(vv1.w + BN_EPS_)) + be1.w, 0.f);

    if (LAST) {
        float4 w30 = ((const float4*)W3)[fg * 2], w31 = ((const float4*)W3)[fg * 2 + 1];
        float p = o0 * w30.x + o1 * w30.y + o2 * w30.z + o3 * w30.w +
                  o4 * w31.x + o5 * w31.y + o6 * w31.z + o7 * w31.w;
#pragma unroll
        for (int off = 1; off < 8; off <<= 1)
            p += __shfl_xor(p, off, 64);
        if (l == 0) hs3[i] = p * di;
    } else {
        if (es == 0) {
            uint4 pk;
            pk.x = (unsigned)f2bf(o0) | ((unsigned)f2bf(o1) << 16);
            pk.y = (unsigned)f2bf(o2) | ((unsigned)f2bf(o3) << 16);
            pk.z = (unsigned)f2bf(o4) | ((unsigned)f2bf(o5) << 16);
            pk.w = (unsigned)f2bf(o6) | ((unsigned)f2bf(o7) << 16);
            ((uint4*)y)[(long)i * 8 + fg] = pk;
        }
    }
}

// ---------------- layer-3 pull + sigmoid (8 loads in flight) ----------------
__global__ __launch_bounds__(256) void gather3(const int* __restrict__ row_ptr,
                                               const int* __restrict__ csr_src,
                                               const float* __restrict__ hs3,
                                               const float* __restrict__ dinv,
                                               const float* __restrict__ b3,
                                               float* __restrict__ out, int n) {
    int i = blockIdx.x * 256 + threadIdx.x;
    if (i >= n) return;
    int beg = row_ptr[i], end = row_ptr[i + 1];
    float s0 = hs3[i], s1 = 0.f, s2 = 0.f, s3 = 0.f;
    float s4 = 0.f, s5 = 0.f, s6 = 0.f, s7 = 0.f;
    int k = beg;
    for (; k + 8 <= end; k += 8) {
        s0 += hs3[csr_src[k]];
        s1 += hs3[csr_src[k + 1]];
        s2 += hs3[csr_src[k + 2]];
        s3 += hs3[csr_src[k + 3]];
        s4 += hs3[csr_src[k + 4]];
        s5 += hs3[csr_src[k + 5]];
        s6 += hs3[csr_src[k + 6]];
        s7 += hs3[csr_src[k + 7]];
    }
    for (; k < end; k++) s0 += hs3[csr_src[k]];
    float z = dinv[i] * (((s0 + s1) + (s2 + s3)) + ((s4 + s5) + (s6 + s7))) + b3[0];
    out[i] = 1.f / (1.f + expf(-z));
}

extern "C" void kernel_launch(void* const* d_in, const int* in_sizes, int n_in,
                              void* d_out, int out_size, void* d_ws, size_t ws_size,
                              hipStream_t stream) {
    const int N = N_NODES;
    const int E = E_EDGES;

    const float* x   = (const float*)d_in[0];
    const int*   ei  = (const int*)d_in[1];   // [2, E]: row0=src, row1=dst
    const float* W1  = (const float*)d_in[2];
    const float* b1  = (const float*)d_in[3];
    const float* W2  = (const float*)d_in[4];
    const float* b2  = (const float*)d_in[5];
    const float* W3  = (const float*)d_in[6];
    const float* b3  = (const float*)d_in[7];
    const float* g1  = (const float*)d_in[8];
    const float* bt1 = (const float*)d_in[9];
    const float* m1  = (const float*)d_in[10];
    const float* v1  = (const float*)d_in[11];
    const float* g2  = (const float*)d_in[12];
    const float* bt2 = (const float*)d_in[13];
    const float* m2  = (const float*)d_in[14];
    const float* v2  = (const float*)d_in[15];
    float* out = (float*)d_out;

    // workspace layout (4-byte units)
    int*    wsi         = (int*)d_ws;
    float*  dinv        = (float*)wsi;                    // N
    float*  hs3         = (float*)(wsi + (long)N);        // N
    int*    row_ptr     = wsi + 2L * N;                   // N+1 (pad 16)
    int*    histPB      = wsi + 3L * N + 16;              // NBUCK*PB
    int*    bucket_tot  = histPB + NBUCK * PB;            // NBUCK (pad 400)
    int*    bucket_base = bucket_tot + 400;               // NBUCK+1 (pad 400)
    int*    csr_src     = bucket_base + 400;              // E
    ushort* hsb         = (ushort*)(csr_src + (long)E);   // (N+1)*64 bf16 (16B-aligned)
    unsigned* yb        = (unsigned*)(csr_src + (long)E + 32L * (N + 1)); // N*32 uints
    int*    ebuf        = (int*)hsb;                      // E ints, aliases hsb

    // ---- CSR build (bucketed counting sort, coalesced writes) ----
    passA1_hist<<<PB, 512, 0, stream>>>(ei, histPB);
    scan_rows<<<NBUCK, 256, 0, stream>>>(histPB, bucket_tot);
    scan_totals<<<1, 512, 0, stream>>>(bucket_tot, bucket_base, row_ptr);
    passA2_sorted<<<PB, 512, 0, stream>>>(ei, histPB, bucket_base, ebuf);
    passB_sorted<<<NBUCK, 256, 0, stream>>>(ebuf, bucket_base, row_ptr, csr_src, dinv);

    // ---- layer 1 ----
    gemm_bf16<IN_DIM_, false><<<(N + 63) / 64, 256, 0, stream>>>(x, W1, dinv, hsb);
    gather_feat<false><<<N / 4, 256, 0, stream>>>(row_ptr, csr_src, hsb, dinv,
                                                  b1, g1, bt1, m1, v1, yb, W3, hs3, N);
    // ---- layer 2 (+ fused gemv3) ----
    gemm_bf16<HID_, true><<<(N + 63) / 64, 256, 0, stream>>>(yb, W2, dinv, hsb);
    gather_feat<true><<<N / 4, 256, 0, stream>>>(row_ptr, csr_src, hsb, dinv,
                                                 b2, g2, bt2, m2, v2, yb, W3, hs3, N);
    // ---- layer 3 ----
    gather3<<<(N + 255) / 256, 256, 0, stream>>>(row_ptr, csr_src, hs3, dinv, b3, out, N);
}